// Round 2
// baseline (231.942 us; speedup 1.0000x reference)
//
#include <hip/hip_runtime.h>
#include <math.h>

#define VOCAB 32000
#define D 768
#define S 512
#define W 300
#define B 64
#define LMAX 4
#define WPW 4  // words per wave

typedef float f32x4 __attribute__((ext_vector_type(4)));

// ---------------------------------------------------------------------------
// Kernel 1: per-batch "first break" scan.
// brk[w] = (en < S) && (span <= 0); first[b] = min w with brk, else W.
// fill_id[b] = wid[b, clip(first, 0, W-1)].
// ---------------------------------------------------------------------------
__global__ __launch_bounds__(64) void find_first_kernel(
    const int* __restrict__ word_index,  // (B, W, 3)
    int* __restrict__ first_out,         // (B)
    int* __restrict__ fill_id_out)       // (B)
{
    const int b = blockIdx.x;
    const int lane = threadIdx.x;  // 0..63
    int my_first = W;
    for (int w = lane; w < W; w += 64) {
        const int base = (b * W + w) * 3;
        const int st = word_index[base + 1];
        const int en = word_index[base + 2];
        if (en < S && (en - st) <= 0) my_first = min(my_first, w);
    }
    #pragma unroll
    for (int off = 32; off > 0; off >>= 1)
        my_first = min(my_first, __shfl_xor(my_first, off));
    if (lane == 0) {
        first_out[b] = my_first;
        const int fw = min(my_first, W - 1);
        fill_id_out[b] = word_index[(b * W + fw) * 3 + 0];
    }
}

__device__ __forceinline__ float wave_bcast_sum(float p) {
    #pragma unroll
    for (int off = 32; off > 0; off >>= 1) p += __shfl_xor(p, off);
    return p;
}

// ---------------------------------------------------------------------------
// Kernel 2: one wave per 4 consecutive words of one batch (W=300 = 75*4, so a
// wave never crosses a batch boundary).
//
// MLP restructure vs. one-wave-per-word:
//  - metadata for 4 words = 12 contiguous ints -> scalar loads, one dependent
//    scalar-fetch chain amortized over 4 words.
//  - all 4 output base rows (emb[wid] or emb[fill_id]) issued up-front:
//    12 independent 1KB global loads in flight per wave (was 3).
//  - copy/fill words (majority) then reduce to "store the prefetched row".
//  - pooling words consume their prefetched we row with the same online
//    softmax single pass as before (depth-1 char-row prefetch kept).
// Live set: we[4][3] = 48 VGPR + pooling temps (~36) + addressing -> fits
// under the 128-VGPR cap from __launch_bounds__(256, 4).
// ---------------------------------------------------------------------------
__global__ __launch_bounds__(256, 4) void pool_kernel(
    const float* __restrict__ ernie,      // (B, S, D)
    const float* __restrict__ emb,        // (VOCAB, D)
    const int*   __restrict__ word_index, // (B, W, 3)
    const int*   __restrict__ first_arr,  // (B)
    const int*   __restrict__ fill_arr,   // (B)
    float* __restrict__ out)              // (B, W, D)
{
    int gw = (int)((blockIdx.x * blockDim.x + threadIdx.x) >> 6);
    gw = __builtin_amdgcn_readfirstlane(gw);  // force wave-uniform/SGPR
    const int lane = threadIdx.x & 63;

    const int b  = gw / (W / WPW);              // 75 wave-groups per batch
    const int w0 = (gw - b * (W / WPW)) * WPW;  // first word of this wave

    // ---- metadata for all 4 words: 12 contiguous ints, scalar loads ----
    const int base = (b * W + w0) * 3;
    int wid[WPW], st[WPW], en[WPW];
    #pragma unroll
    for (int i = 0; i < WPW; ++i) {
        wid[i] = word_index[base + 3 * i + 0];
        st[i]  = word_index[base + 3 * i + 1];
        en[i]  = word_index[base + 3 * i + 2];
    }
    const int first  = first_arr[b];
    const int fillid = fill_arr[b];

    // ---- issue all 4 base-row loads up-front (12 independent 1KB loads) ----
    // fill words read emb[fill_id]; everything else reads emb[wid].
    const f32x4* __restrict__ embv = (const f32x4*)emb;
    f32x4 we[WPW][3];
    #pragma unroll
    for (int i = 0; i < WPW; ++i) {
        const int rid = (w0 + i >= first) ? fillid : wid[i];  // scalar select
        const f32x4* rp = embv + (size_t)rid * 192;
        we[i][0] = rp[lane];
        we[i][1] = rp[lane + 64];
        we[i][2] = rp[lane + 128];
    }

    f32x4* __restrict__ outp0 = (f32x4*)out + (size_t)(b * W + w0) * 192;
    const f32x4* __restrict__ erow = (const f32x4*)ernie + (size_t)b * S * 192;

    #pragma unroll
    for (int i = 0; i < WPW; ++i) {
        f32x4* __restrict__ outp = outp0 + (size_t)i * 192;
        const bool do_pool = (w0 + i < first) && (en[i] < S);  // wave-uniform

        if (!do_pool) {
            // fill path (w >= first -> emb[fill_id]) or out-of-range path
            // (en >= S -> we): row already prefetched into we[i].
            __builtin_nontemporal_store(we[i][0], &outp[lane]);
            __builtin_nontemporal_store(we[i][1], &outp[lane + 64]);
            __builtin_nontemporal_store(we[i][2], &outp[lane + 128]);
            continue;
        }

        // ---- pooling path: online softmax, single pass over char rows ----
        const int span_eff = min(max(en[i] - st[i], 1), LMAX);

        float m = -INFINITY, denom = 0.f;
        f32x4 acc0 = 0.f, acc1 = 0.f, acc2 = 0.f;

        const int p0 = min(max(st[i], 0), S - 1);
        f32x4 c0 = erow[p0 * 192 + lane];
        f32x4 c1 = erow[p0 * 192 + lane + 64];
        f32x4 c2 = erow[p0 * 192 + lane + 128];

        #pragma unroll
        for (int l = 0; l < LMAX; ++l) {
            if (l >= span_eff) break;  // scalar branch (span_eff is SGPR)
            f32x4 n0, n1, n2;
            if (l + 1 < span_eff) {    // depth-1 prefetch of next row
                const int pn = min(max(st[i] + l + 1, 0), S - 1);
                n0 = erow[pn * 192 + lane];
                n1 = erow[pn * 192 + lane + 64];
                n2 = erow[pn * 192 + lane + 128];
            } else {
                n0 = c0; n1 = c1; n2 = c2;
            }
            f32x4 pv = c0 * we[i][0] + c1 * we[i][1] + c2 * we[i][2];
            float p = pv.x + pv.y + pv.z + pv.w;
            p = wave_bcast_sum(p);           // all lanes hold full dot
            const float mn = fmaxf(m, p);
            const float scale = __expf(m - mn);  // 1st iter: exp(-inf)=0
            const float e = __expf(p - mn);
            denom = denom * scale + e;
            acc0 = acc0 * scale + e * c0;
            acc1 = acc1 * scale + e * c1;
            acc2 = acc2 * scale + e * c2;
            m = mn;
            c0 = n0; c1 = n1; c2 = n2;
        }

        const float inv = 1.f / denom;
        __builtin_nontemporal_store(acc0 * inv, &outp[lane]);
        __builtin_nontemporal_store(acc1 * inv, &outp[lane + 64]);
        __builtin_nontemporal_store(acc2 * inv, &outp[lane + 128]);
    }
}

extern "C" void kernel_launch(void* const* d_in, const int* in_sizes, int n_in,
                              void* d_out, int out_size, void* d_ws, size_t ws_size,
                              hipStream_t stream) {
    const float* ernie      = (const float*)d_in[0];  // (B, S, D) fp32
    const float* emb        = (const float*)d_in[1];  // (VOCAB, D) fp32
    const int*   word_index = (const int*)d_in[2];    // (B, W, 3) int32
    float* out = (float*)d_out;                       // (B, W, D) fp32

    int* first_arr = (int*)d_ws;        // B ints
    int* fill_arr  = first_arr + B;     // B ints

    find_first_kernel<<<B, 64, 0, stream>>>(word_index, first_arr, fill_arr);

    // B*W = 19200 words; 4 words/wave, 4 waves/block -> 16 words/block.
    const int grid = (B * W) / (WPW * 4);  // 1200 blocks
    pool_kernel<<<grid, 256, 0, stream>>>(ernie, emb, word_index,
                                          first_arr, fill_arr, out);
}

// Round 3
// 222.032 us; speedup vs baseline: 1.0446x; 1.0446x over previous
//
#include <hip/hip_runtime.h>
#include <math.h>

#define VOCAB 32000
#define D 768
#define S 512
#define W 300
#define B 64
#define LMAX 4

typedef float f32x4 __attribute__((ext_vector_type(4)));

// ---------------------------------------------------------------------------
// Kernel 1: prep. Per batch: first-break scan + fill id, then emit one 16B
// descriptor per word so the hot kernel's prologue is a single scalar load.
//   mode 0 (copy): out = emb[rid]           desc = {rid,    0,        0,    0}
//   mode 1 (pool): softmax-pool over chars  desc = {rid, b*S+p0, span_eff, 1}
// Copy covers both the fill path (w >= first -> rid = fill_id) and the
// out-of-range path (en >= S -> rid = wid).
// ---------------------------------------------------------------------------
__global__ __launch_bounds__(64) void prep_kernel(
    const int* __restrict__ word_index,  // (B, W, 3)
    int4* __restrict__ desc)             // (B, W)
{
    const int b = blockIdx.x;
    const int lane = threadIdx.x;  // 0..63

    int my_first = W;
    for (int w = lane; w < W; w += 64) {
        const int base = (b * W + w) * 3;
        const int st = word_index[base + 1];
        const int en = word_index[base + 2];
        if (en < S && en <= st) my_first = min(my_first, w);
    }
    #pragma unroll
    for (int off = 32; off > 0; off >>= 1)
        my_first = min(my_first, __shfl_xor(my_first, off));
    const int first = my_first;  // butterfly -> all lanes hold the min

    const int fw = min(first, W - 1);
    const int fillid = word_index[(b * W + fw) * 3 + 0];  // same addr all lanes

    for (int w = lane; w < W; w += 64) {
        const int base = (b * W + w) * 3;
        const int wid = word_index[base + 0];
        const int st  = word_index[base + 1];
        const int en  = word_index[base + 2];
        int4 d;
        if (w >= first) {
            d.x = fillid; d.y = 0; d.z = 0; d.w = 0;
        } else if (en >= S) {
            d.x = wid; d.y = 0; d.z = 0; d.w = 0;
        } else {
            // pool path: en < S and (since w < first) en > st, so rows
            // p0..p0+span-1 are all < S after the clamp below.
            const int p0 = min(max(st, 0), S - 1);
            d.x = wid;
            d.y = b * S + p0;                       // global ernie row
            d.z = min(max(en - st, 1), LMAX);       // span_eff in 1..4
            d.w = 1;
        }
        desc[b * W + w] = d;
    }
}

// ---------------------------------------------------------------------------
// Kernel 2: one wave per word. Single scalar-load prologue (descriptor),
// then ALL row loads issued up-front (3 we + 3*span char f32x4 = up to 15KB
// in flight, one latency epoch). Flat softmax: 4 independent dots -> one
// batched butterfly -> in-lane softmax -> weighted sum. No online-rescale
// serial chain. Char rows are nontemporal (single-use, keep L2 for emb).
// No occupancy cap: let regalloc keep all rows live (expect ~90-120 VGPR).
// ---------------------------------------------------------------------------
__global__ __launch_bounds__(256) void pool_kernel(
    const float* __restrict__ ernie,   // (B, S, D)
    const float* __restrict__ emb,     // (VOCAB, D)
    const int4* __restrict__ desc,     // (B, W)
    float* __restrict__ out)           // (B, W, D)
{
    int gw = (int)((blockIdx.x * blockDim.x + threadIdx.x) >> 6);
    gw = __builtin_amdgcn_readfirstlane(gw);  // wave-uniform -> SGPR
    const int lane = threadIdx.x & 63;

    const int4 d = desc[gw];  // uniform address -> s_load_dwordx4

    f32x4* __restrict__ outp = (f32x4*)out + (size_t)gw * 192;
    const f32x4* __restrict__ rp = (const f32x4*)emb + (size_t)d.x * 192;

    if (d.w == 0) {  // ---- copy path (fill or out-of-range) ----
        __builtin_nontemporal_store(rp[lane],       &outp[lane]);
        __builtin_nontemporal_store(rp[lane + 64],  &outp[lane + 64]);
        __builtin_nontemporal_store(rp[lane + 128], &outp[lane + 128]);
        return;
    }

    // ---- pooling path ----
    const int span = d.z;  // 1..4, wave-uniform (SGPR) -> scalar branches
    const f32x4* __restrict__ cb = (const f32x4*)ernie + (size_t)d.y * 192;

    // Issue everything up-front: one memory-latency epoch.
    f32x4 we0 = rp[lane], we1 = rp[lane + 64], we2 = rp[lane + 128];

    f32x4 c[LMAX][3];  // statically indexed everywhere (no scratch)
    c[0][0] = __builtin_nontemporal_load(&cb[lane]);
    c[0][1] = __builtin_nontemporal_load(&cb[lane + 64]);
    c[0][2] = __builtin_nontemporal_load(&cb[lane + 128]);
    if (span > 1) {
        c[1][0] = __builtin_nontemporal_load(&cb[192 + lane]);
        c[1][1] = __builtin_nontemporal_load(&cb[192 + lane + 64]);
        c[1][2] = __builtin_nontemporal_load(&cb[192 + lane + 128]);
    }
    if (span > 2) {
        c[2][0] = __builtin_nontemporal_load(&cb[384 + lane]);
        c[2][1] = __builtin_nontemporal_load(&cb[384 + lane + 64]);
        c[2][2] = __builtin_nontemporal_load(&cb[384 + lane + 128]);
    }
    if (span > 3) {
        c[3][0] = __builtin_nontemporal_load(&cb[576 + lane]);
        c[3][1] = __builtin_nontemporal_load(&cb[576 + lane + 64]);
        c[3][2] = __builtin_nontemporal_load(&cb[576 + lane + 128]);
    }

    // Per-lane partial dots (independent). Inactive lanes get -inf so the
    // butterfly stays NaN-free (-inf + -inf = -inf) and exp() yields 0.
    f32x4 pv0 = c[0][0] * we0 + c[0][1] * we1 + c[0][2] * we2;
    float s0 = pv0.x + pv0.y + pv0.z + pv0.w;
    float s1 = -INFINITY, s2 = -INFINITY, s3 = -INFINITY;
    if (span > 1) {
        f32x4 pv = c[1][0] * we0 + c[1][1] * we1 + c[1][2] * we2;
        s1 = pv.x + pv.y + pv.z + pv.w;
    }
    if (span > 2) {
        f32x4 pv = c[2][0] * we0 + c[2][1] * we1 + c[2][2] * we2;
        s2 = pv.x + pv.y + pv.z + pv.w;
    }
    if (span > 3) {
        f32x4 pv = c[3][0] * we0 + c[3][1] * we1 + c[3][2] * we2;
        s3 = pv.x + pv.y + pv.z + pv.w;
    }

    // One batched butterfly: 4 interleaved chains, single latency chain.
    #pragma unroll
    for (int off = 32; off > 0; off >>= 1) {
        s0 += __shfl_xor(s0, off);
        s1 += __shfl_xor(s1, off);
        s2 += __shfl_xor(s2, off);
        s3 += __shfl_xor(s3, off);
    }

    // In-lane flat softmax (every lane holds all scores; no more cross-lane).
    const float mx = fmaxf(fmaxf(s0, s1), fmaxf(s2, s3));
    const float e0 = __expf(s0 - mx);
    const float e1 = __expf(s1 - mx);  // exp(-inf) = 0 for inactive
    const float e2 = __expf(s2 - mx);
    const float e3 = __expf(s3 - mx);
    const float inv = 1.f / (e0 + e1 + e2 + e3);

    f32x4 a0 = e0 * c[0][0], a1 = e0 * c[0][1], a2 = e0 * c[0][2];
    if (span > 1) { a0 += e1 * c[1][0]; a1 += e1 * c[1][1]; a2 += e1 * c[1][2]; }
    if (span > 2) { a0 += e2 * c[2][0]; a1 += e2 * c[2][1]; a2 += e2 * c[2][2]; }
    if (span > 3) { a0 += e3 * c[3][0]; a1 += e3 * c[3][1]; a2 += e3 * c[3][2]; }

    __builtin_nontemporal_store(a0 * inv, &outp[lane]);
    __builtin_nontemporal_store(a1 * inv, &outp[lane + 64]);
    __builtin_nontemporal_store(a2 * inv, &outp[lane + 128]);
}

extern "C" void kernel_launch(void* const* d_in, const int* in_sizes, int n_in,
                              void* d_out, int out_size, void* d_ws, size_t ws_size,
                              hipStream_t stream) {
    const float* ernie      = (const float*)d_in[0];  // (B, S, D) fp32
    const float* emb        = (const float*)d_in[1];  // (VOCAB, D) fp32
    const int*   word_index = (const int*)d_in[2];    // (B, W, 3) int32
    float* out = (float*)d_out;                       // (B, W, D) fp32

    int4* desc = (int4*)d_ws;  // B*W*16 = 307200 bytes of workspace

    prep_kernel<<<B, 64, 0, stream>>>(word_index, desc);

    // One wave per word: B*W = 19200 waves, 4 waves/block -> 4800 blocks.
    const int grid = (B * W) / 4;
    pool_kernel<<<grid, 256, 0, stream>>>(ernie, emb, desc, out);
}